// Round 7
// baseline (32.866 us; speedup 1.0000x reference)
//
#include <hip/hip_runtime.h>
#include <stdint.h>

#define SEQ  8192
#define NB   128
#define MAXP 4096
#define NT   512
#define RED  4                     // blocks per sequence: redundant chain, split emission
#define NCH  256                   // 32-wide chunks per sequence

__device__ __forceinline__ bool haszero8(uint64_t v) {
    return ((v - 0x0101010101010101ULL) & ~v & 0x8080808080808080ULL) != 0ULL;
}
__device__ __forceinline__ bool distinct8(uint64_t w) {
    uint64_t r1 = (w >> 8)  | (w << 56);
    uint64_t r2 = (w >> 16) | (w << 48);
    uint64_t r3 = (w >> 24) | (w << 40);
    uint64_t r4 = (w >> 32) | (w << 32);
    return !(haszero8(w ^ r1) | haszero8(w ^ r2) | haszero8(w ^ r3) | haszero8(w ^ r4));
}
__device__ __forceinline__ uint32_t pack4(int4 v) {
    return (uint32_t)(v.x & 255) | ((uint32_t)(v.y & 255) << 8) |
           ((uint32_t)(v.z & 255) << 16) | ((uint32_t)(v.w & 255) << 24);
}
__device__ __forceinline__ uint32_t bsel16(uint4 f, uint32_t b) {
    uint32_t w01 = (b & 4u) ? f.y : f.x;
    uint32_t w23 = (b & 4u) ? f.w : f.z;
    uint32_t w   = (b & 8u) ? w23 : w01;
    return (w >> ((b & 3u) << 3)) & 255u;
}
// r.byte[i] = g.byte[f.byte[i]]  (byte values in [0,16)) -- proven rounds 5-6
__device__ __forceinline__ uint4 comp16(uint4 g, uint4 f) {
    uint4 r;
#if __has_builtin(__builtin_amdgcn_perm)
    #define C16W(fw, out) do { \
        uint32_t sel = (fw) & 0x07070707u; \
        uint32_t lo = __builtin_amdgcn_perm(g.y, g.x, sel); \
        uint32_t hi = __builtin_amdgcn_perm(g.w, g.z, sel); \
        uint32_t m = ((fw) & 0x08080808u) >> 3; m = (m << 8) - m; \
        out = (lo & ~m) | (hi & m); } while (0)
    C16W(f.x, r.x); C16W(f.y, r.y); C16W(f.z, r.z); C16W(f.w, r.w);
    #undef C16W
#else
    #define C16B(fw, out) do { uint32_t o = 0; \
        o |= bsel16(g, (fw) & 15u); \
        o |= bsel16(g, ((fw) >> 8) & 15u) << 8; \
        o |= bsel16(g, ((fw) >> 16) & 15u) << 16; \
        o |= bsel16(g, ((fw) >> 24) & 15u) << 24; \
        out = o; } while (0)
    C16B(f.x, r.x); C16B(f.y, r.y); C16B(f.z, r.z); C16B(f.w, r.w);
    #undef C16B
#endif
    return r;
}

__global__ __launch_bounds__(NT) void ep_fused(const int* __restrict__ tokens,
                                               int* __restrict__ out) {
    __shared__ uint32_t tok32[2056];     // 8192 tokens u8-packed + 32B zero pad
    __shared__ uint16_t stop16[512];
    __shared__ uint32_t stopb[258];
    __shared__ uint8_t  sizes8[SEQ];
    __shared__ uint32_t exitf32[NCH * 4];
    __shared__ uint32_t cntf32[NCH * 4];
    __shared__ uint8_t  entry_s[NCH];
    __shared__ uint16_t pbase_s[NCH];
    __shared__ uint16_t starts_s[4100];
    __shared__ int wsum_s[8];
    __shared__ int S_s[4];

    const int bx = blockIdx.x;
    const int b = bx >> 2, qc = bx & 3;          // sequence, emission quarter
    const int tid = threadIdx.x;
    const int lane = tid & 63, wid = tid >> 6;

    // ---- A: coalesced load, pack tokens to u8 (proven) ----
    {
        const int4* t4 = (const int4*)(tokens + (size_t)b * SEQ);
        #pragma unroll
        for (int k = 0; k < 4; ++k) { int g = k * NT + tid; tok32[g] = pack4(t4[g]); }
        if (tid < 8) tok32[2048 + tid] = 0u;
    }
    __syncthreads();

    // ---- B: stop bits (exact integer test; proven) ----
    {
        const int base = tid * 4;
        uint64_t win = (uint64_t)tok32[base] | ((uint64_t)tok32[base + 1] << 32);
        uint32_t bits = 0;
        #pragma unroll
        for (int k = 0; k < 4; ++k) {
            uint32_t nx = tok32[base + 2 + k];
            #pragma unroll
            for (int m = 0; m < 4; ++m) {
                int j = tid * 16 + k * 4 + m;
                if (j <= SEQ - 8 && distinct8(win)) bits |= (1u << (k * 4 + m));
                win = (win >> 8) | ((uint64_t)(nx & 255u) << 56);
                nx >>= 8;
            }
        }
        stop16[tid] = (uint16_t)bits;
    }
    __syncthreads();
    if (tid < 256) stopb[tid] = (uint32_t)stop16[2 * tid] | ((uint32_t)stop16[2 * tid + 1] << 16);
    if (tid < 2) stopb[256 + tid] = 0u;
    __syncthreads();

    // ---- Bs: sizes (proven formula) ----
    {
        #pragma unroll 4
        for (int m = 0; m < 16; ++m) {
            int i = tid * 16 + m;
            int bp = i + 2, w = bp >> 5;
            uint64_t comb = (uint64_t)stopb[w] | ((uint64_t)stopb[w + 1] << 32);
            uint32_t win14 = (uint32_t)(comb >> (bp & 31)) & 0x3FFFu;
            int sz = win14 ? (2 + __builtin_ctz(win14)) : min(16, SEQ - i);
            sizes8[i] = (uint8_t)sz;
        }
    }
    __syncthreads();

    // ---- T: chunk transfer functions (proven) ----
    {
        const int ch = tid >> 1, e0 = (tid & 1) << 3;
        const int cb = ch * 32, lim = cb + 32;
        int pp[8], cc[8];
        #pragma unroll
        for (int k = 0; k < 8; ++k) { pp[k] = cb + e0 + k; cc[k] = 0; }
        for (int it = 0; it < 17; ++it) {
            bool any = false;
            #pragma unroll
            for (int k = 0; k < 8; ++k) {
                bool a = pp[k] < lim;
                int s = (int)sizes8[a ? pp[k] : cb];
                if (a) { cc[k] += 1; pp[k] += s; any = true; }
            }
            if (!any) break;
        }
        uint32_t xw0 = 0, xw1 = 0, cw0 = 0, cw1 = 0;
        #pragma unroll
        for (int k = 0; k < 4; ++k) {
            xw0 |= (uint32_t)(pp[k] - lim) << (k * 8);
            cw0 |= (uint32_t)cc[k] << (k * 8);
            xw1 |= (uint32_t)(pp[k + 4] - lim) << (k * 8);
            cw1 |= (uint32_t)cc[k + 4] << (k * 8);
        }
        int wb = (ch << 2) + ((tid & 1) << 1);
        exitf32[wb] = xw0; exitf32[wb + 1] = xw1;
        cntf32[wb]  = cw0; cntf32[wb + 1]  = cw1;
    }
    __syncthreads();

    // ---- S: wave-0 function scan -> chunk entries (proven) ----
    if (tid < 64) {
        const uint4* xf4 = (const uint4*)exitf32;
        uint4 f0 = xf4[tid * 4], f1 = xf4[tid * 4 + 1],
              f2 = xf4[tid * 4 + 2], f3 = xf4[tid * 4 + 3];
        uint4 g = comp16(f1, f0);
        g = comp16(f2, g);
        g = comp16(f3, g);
        #pragma unroll
        for (int d = 1; d < 64; d <<= 1) {
            uint4 o;
            o.x = (uint32_t)__shfl_up((int)g.x, d);
            o.y = (uint32_t)__shfl_up((int)g.y, d);
            o.z = (uint32_t)__shfl_up((int)g.z, d);
            o.w = (uint32_t)__shfl_up((int)g.w, d);
            if (tid >= d) g = comp16(g, o);
        }
        uint4 E;
        E.x = (uint32_t)__shfl_up((int)g.x, 1);
        E.y = (uint32_t)__shfl_up((int)g.y, 1);
        E.z = (uint32_t)__shfl_up((int)g.z, 1);
        E.w = (uint32_t)__shfl_up((int)g.w, 1);
        if (tid == 0) E = make_uint4(0x03020100u, 0x07060504u, 0x0B0A0908u, 0x0F0E0D0Cu);
        uint32_t e0 = E.x & 255u;
        uint32_t e1 = bsel16(f0, e0);
        uint32_t e2 = bsel16(f1, e1);
        uint32_t e3 = bsel16(f2, e2);
        entry_s[tid * 4 + 0] = (uint8_t)e0;
        entry_s[tid * 4 + 1] = (uint8_t)e1;
        entry_s[tid * 4 + 2] = (uint8_t)e2;
        entry_s[tid * 4 + 3] = (uint8_t)e3;
    }
    __syncthreads();

    // ---- C2: per-chunk count + prefix sum -> patch bases (proven) ----
    {
        int cnt = 0;
        if (tid < NCH) cnt = (int)((const uint8_t*)cntf32)[tid * 16 + (int)entry_s[tid]];
        int inc = cnt;
        #pragma unroll
        for (int d = 1; d < 64; d <<= 1) { int o = __shfl_up(inc, d); if (lane >= d) inc += o; }
        if (lane == 63) wsum_s[wid] = inc;
        __syncthreads();
        int off = 0;
        for (int w = 0; w < wid; ++w) off += wsum_s[w];
        if (tid < NCH) pbase_s[tid] = (uint16_t)(off + inc - cnt);
        if (tid == NCH - 1) S_s[0] = off + inc;   // total P
    }
    __syncthreads();

    // ---- X: per-chunk expansion (proven) ----
    if (tid < NCH) {
        int pb = (int)pbase_s[tid];
        int p = tid * 32 + (int)entry_s[tid];
        const int lim = tid * 32 + 32;
        while (p < lim) {
            starts_s[pb++] = (uint16_t)p;
            p += (int)sizes8[p];
        }
    }
    __syncthreads();
    {
        const int P = S_s[0];
        for (int i = P + tid; i < 4098; i += NT) starts_s[i] = (uint16_t)SEQ;
    }
    __syncthreads();

    // ---- G: emission of this block's quarter (alignbit-based, coalesced) ----
    {
        int* outp = out + (size_t)b * (MAXP * 16);
        int* outm = out + (size_t)NB * MAXP * 16 + (size_t)b * MAXP;
        #pragma unroll
        for (int it = 0; it < MAXP / RED / NT; ++it) {       // 2 iterations
            const int p = qc * (MAXP / RED) + it * NT + tid;
            const int st = (int)starts_s[p];
            const int sz = (int)starts_s[p + 1] - st;        // 0..16 (0 for p>=P)
            const int base = st >> 2;
            const uint32_t sh = (uint32_t)(st & 3) * 8u;
            uint32_t w0 = tok32[base],     w1 = tok32[base + 1], w2 = tok32[base + 2],
                     w3 = tok32[base + 3], w4 = tok32[base + 4];
            int4* dst = (int4*)outp + (size_t)p * 4;
            #pragma unroll
            for (int j = 0; j < 4; ++j) {
                uint32_t lo = (j == 0) ? w0 : (j == 1) ? w1 : (j == 2) ? w2 : w3;
                uint32_t hi = (j == 0) ? w1 : (j == 1) ? w2 : (j == 2) ? w3 : w4;
                uint32_t pk = (uint32_t)((((uint64_t)hi << 32) | lo) >> sh);
                int rem = sz - 4 * j;
                rem = (rem < 0) ? 0 : (rem > 4 ? 4 : rem);
                uint32_t msk = (uint32_t)((1ULL << (8 * rem)) - 1ULL);
                pk &= msk;
                dst[j] = make_int4((int)(pk & 255u), (int)((pk >> 8) & 255u),
                                   (int)((pk >> 16) & 255u), (int)(pk >> 24));
            }
            outm[p] = (st < SEQ) ? 1 : 0;
        }
    }
}

extern "C" void kernel_launch(void* const* d_in, const int* in_sizes, int n_in,
                              void* d_out, int out_size, void* d_ws, size_t ws_size,
                              hipStream_t stream) {
    const int* tokens = (const int*)d_in[0];
    int* out = (int*)d_out;
    ep_fused<<<dim3(NB * RED), dim3(NT), 0, stream>>>(tokens, out);
}